// Round 1
// baseline (372.434 us; speedup 1.0000x reference)
//
#include <hip/hip_runtime.h>
#include <cstdint>
#include <cstddef>

// Problem constants
#define BB 8
#define CC 512
#define NN 4096   // H*W
// heads = 8, dh = 64, groups = 32, group size = 16 channels

typedef __bf16 bf16x8 __attribute__((ext_vector_type(8)));
typedef float floatx4 __attribute__((ext_vector_type(4)));

__device__ __forceinline__ unsigned short f2bf(float f) {
  unsigned int u = __builtin_bit_cast(unsigned int, f);
  u += 0x7FFFu + ((u >> 16) & 1u);   // round-to-nearest-even
  return (unsigned short)(u >> 16);
}

__device__ __forceinline__ void async16(const void* g, void* l) {
  __builtin_amdgcn_global_load_lds(
      (const __attribute__((address_space(1))) unsigned int*)g,
      (__attribute__((address_space(3))) unsigned int*)l, 16, 0, 0);
}

__device__ __forceinline__ floatx4 mfma16(bf16x8 a, bf16x8 b, floatx4 c) {
  return __builtin_amdgcn_mfma_f32_16x16x32_bf16(a, b, c, 0, 0, 0);
}

// ---------------------------------------------------------------- cvt f32->bf16
__global__ void cvt_bf16(const float* __restrict__ src, unsigned short* __restrict__ dst, int n) {
  int i = blockIdx.x * 256 + threadIdx.x;
  if (i < n) dst[i] = f2bf(src[i]);
}

// ---------------------------------------------------------------- GN stats
// one block per (b, g); 16 contiguous channels x 4096 = 65536 contiguous floats
__global__ __launch_bounds__(256) void gn_stats(
    const float* __restrict__ x, const float* __restrict__ scale,
    const float* __restrict__ bias, float* __restrict__ cA, float* __restrict__ cB) {
  int b = blockIdx.x >> 5, g = blockIdx.x & 31;
  const float4* p = (const float4*)(x + (size_t)(b * CC + g * 16) * NN);
  float s = 0.f, sq = 0.f;
  for (int i = threadIdx.x; i < 16384; i += 256) {
    float4 v = p[i];
    s += (v.x + v.y) + (v.z + v.w);
    sq += (v.x * v.x + v.y * v.y) + (v.z * v.z + v.w * v.w);
  }
#pragma unroll
  for (int off = 32; off > 0; off >>= 1) {
    s += __shfl_down(s, off);
    sq += __shfl_down(sq, off);
  }
  __shared__ float rs[4], rq[4], mv[2];
  int wave = threadIdx.x >> 6, lane = threadIdx.x & 63;
  if (lane == 0) { rs[wave] = s; rq[wave] = sq; }
  __syncthreads();
  if (threadIdx.x == 0) {
    float tS = (rs[0] + rs[1]) + (rs[2] + rs[3]);
    float tQ = (rq[0] + rq[1]) + (rq[2] + rq[3]);
    float mean = tS * (1.f / 65536.f);
    float var = tQ * (1.f / 65536.f) - mean * mean;
    mv[0] = mean;
    mv[1] = rsqrtf(var + 1e-5f);
  }
  __syncthreads();
  if (threadIdx.x < 16) {
    int c = g * 16 + threadIdx.x;
    float a = mv[1] * scale[c];
    cA[b * CC + c] = a;
    cB[b * CC + c] = bias[c] - mv[0] * a;
  }
}

// ---------------------------------------------------------------- normalize + transpose
// x (B,C,N) f32  ->  hT (B,N,C) bf16,  h = x*a[c]+b[c]
__global__ __launch_bounds__(256) void gn_transpose(
    const float* __restrict__ x, const float* __restrict__ cA,
    const float* __restrict__ cB, unsigned short* __restrict__ hT) {
  int n0 = blockIdx.x * 64, c0 = blockIdx.y * 64, b = blockIdx.z;
  __shared__ float tile[64][65];
  const float* xb = x + (size_t)(b * CC + c0) * NN + n0;
  int r = threadIdx.x >> 2, j0 = threadIdx.x & 3;
#pragma unroll
  for (int j = j0; j < 16; j += 4) {
    float4 v = *(const float4*)(xb + (size_t)r * NN + j * 4);
    tile[r][j * 4 + 0] = v.x; tile[r][j * 4 + 1] = v.y;
    tile[r][j * 4 + 2] = v.z; tile[r][j * 4 + 3] = v.w;
  }
  __syncthreads();
  int nn = threadIdx.x >> 2, cs = (threadIdx.x & 3) * 16;
  const float* a = cA + b * CC + c0 + cs;
  const float* bb = cB + b * CC + c0 + cs;
  alignas(16) unsigned short outv[16];
#pragma unroll
  for (int i = 0; i < 16; i++)
    outv[i] = f2bf(tile[cs + i][nn] * a[i] + bb[i]);
  unsigned short* dst = hT + ((size_t)b * NN + n0 + nn) * CC + c0 + cs;
  *(uint4*)dst = *(const uint4*)outv;
  *(uint4*)(dst + 8) = *(const uint4*)(outv + 8);
}

// ---------------------------------------------------------------- GEMM  D = A * BT^T
// A: MxK bf16 row-major, BT: per-batch NxK bf16 row-major (batch stride N*C)
// MODE 0: qkv — rows [0,1024) -> out_qk (b,c,n) bf16; rows [1024,1536) -> out_vT (b,n,c) bf16
// MODE 1: proj — out_f32 = acc + bias + resid, (b,c,n) f32
template <int MODE>
__global__ __launch_bounds__(256) void gemm_bt(
    const unsigned short* __restrict__ A, const unsigned short* __restrict__ BT,
    const float* __restrict__ bias, const float* __restrict__ resid,
    unsigned short* __restrict__ out_qk, unsigned short* __restrict__ out_vT,
    float* __restrict__ out_f32, int M, int K) {
  __shared__ unsigned short As[128 * 64];
  __shared__ unsigned short Bs[128 * 64];
  const int b = blockIdx.z;
  const int n0 = blockIdx.x * 128;
  const int m0 = blockIdx.y * 128;
  const unsigned short* Bb = BT + (size_t)b * NN * CC;
  const int tid = threadIdx.x;
  const int lane = tid & 63, wave = tid >> 6;
  const int wr = wave >> 1, wc = wave & 1;
  const int l15 = lane & 15, quad = lane >> 4;

  floatx4 acc[4][4];
#pragma unroll
  for (int i = 0; i < 4; i++)
#pragma unroll
    for (int j = 0; j < 4; j++) acc[i][j] = (floatx4){0.f, 0.f, 0.f, 0.f};

  for (int k0 = 0; k0 < K; k0 += 64) {
#pragma unroll
    for (int t = 0; t < 4; t++) {
      int q = t * 256 + tid;
      int row = q >> 3, kc = q & 7;
      async16(A + (size_t)(m0 + row) * K + k0 + kc * 8, (char*)As + q * 16);
      async16(Bb + (size_t)(n0 + row) * K + k0 + kc * 8, (char*)Bs + q * 16);
    }
    __syncthreads();
#pragma unroll
    for (int kk = 0; kk < 64; kk += 32) {
      bf16x8 aF[4], bF[4];
#pragma unroll
      for (int mi = 0; mi < 4; mi++)
        aF[mi] = *(const bf16x8*)(As + (wr * 64 + mi * 16 + l15) * 64 + kk + quad * 8);
#pragma unroll
      for (int ni = 0; ni < 4; ni++)
        bF[ni] = *(const bf16x8*)(Bs + (wc * 64 + ni * 16 + l15) * 64 + kk + quad * 8);
#pragma unroll
      for (int mi = 0; mi < 4; mi++)
#pragma unroll
        for (int ni = 0; ni < 4; ni++)
          acc[mi][ni] = mfma16(aF[mi], bF[ni], acc[mi][ni]);
    }
    __syncthreads();
  }

  // epilogue: C/D layout col = lane&15, row = quad*4 + r  [m89-verified]
#pragma unroll
  for (int mi = 0; mi < 4; mi++) {
    int o0 = m0 + wr * 64 + mi * 16 + quad * 4;
#pragma unroll
    for (int ni = 0; ni < 4; ni++) {
      int ncol = n0 + wc * 64 + ni * 16 + l15;
      if (MODE == 0) {
        if (m0 < 1024) {
#pragma unroll
          for (int r = 0; r < 4; r++)
            out_qk[((size_t)b * 1024 + o0 + r) * NN + ncol] =
                f2bf(acc[mi][ni][r] + bias[o0 + r]);
        } else {
          alignas(8) unsigned short pk[4];
#pragma unroll
          for (int r = 0; r < 4; r++) pk[r] = f2bf(acc[mi][ni][r] + bias[o0 + r]);
          *(uint2*)(out_vT + ((size_t)b * NN + ncol) * CC + (o0 - 1024)) = *(const uint2*)pk;
        }
      } else {
#pragma unroll
        for (int r = 0; r < 4; r++) {
          size_t idx = ((size_t)b * CC + o0 + r) * NN + ncol;
          out_f32[idx] = acc[mi][ni][r] + bias[o0 + r] + resid[idx];
        }
      }
    }
  }
}

// ---------------------------------------------------------------- attention per (b,h)
// qk: (B,1024,N) bf16 (q rows 0..511, k rows 512..1023); vT: (B,N,C) bf16
// outT: (B,N,C) bf16;  outT[n][h*64+c] = sum_d softmax(q k^T /8)[c][d] * vT[n][h*64+d]
__global__ __launch_bounds__(256) void attention_k(
    const unsigned short* __restrict__ qk, const unsigned short* __restrict__ vT,
    unsigned short* __restrict__ outT) {
  int bh = blockIdx.x;
  int b = bh >> 3, h = bh & 7;
  const unsigned short* qp = qk + ((size_t)b * 1024 + h * 64) * NN;
  const unsigned short* kp = qp + (size_t)512 * NN;
  const unsigned short* vp = vT + (size_t)b * NN * CC + h * 64;
  unsigned short* op = outT + (size_t)b * NN * CC + h * 64;

  __shared__ char smem[58368];
  unsigned short* Qs = (unsigned short*)smem;             // [64][128] phase A
  unsigned short* Ks = (unsigned short*)(smem + 16384);   // [64][128] phase A
  float* attnF = (float*)smem;                            // [64][66]  (overlays Qs)
  unsigned short* attnB = (unsigned short*)(smem + 17408); // [64][64] bf16
  unsigned short* vTs = (unsigned short*)(smem + 25600);  // [256][64] phase B

  int tid = threadIdx.x, lane = tid & 63, wave = tid >> 6;
  int l15 = lane & 15, quad = lane >> 4;

  // ---- phase A: attn partials, wave w covers n = kk-band w*32 of each 128-chunk
  floatx4 acc[4][4];
#pragma unroll
  for (int i = 0; i < 4; i++)
#pragma unroll
    for (int j = 0; j < 4; j++) acc[i][j] = (floatx4){0.f, 0.f, 0.f, 0.f};

  for (int n0 = 0; n0 < NN; n0 += 128) {
#pragma unroll
    for (int t = 0; t < 4; t++) {
      int q = t * 256 + tid;
      int row = q >> 4, c8 = q & 15;
      async16(qp + (size_t)row * NN + n0 + c8 * 8, (char*)Qs + q * 16);
      async16(kp + (size_t)row * NN + n0 + c8 * 8, (char*)Ks + q * 16);
    }
    __syncthreads();
    int kk = wave * 32;
    bf16x8 aF[4], bF[4];
#pragma unroll
    for (int mi = 0; mi < 4; mi++)
      aF[mi] = *(const bf16x8*)(Qs + (mi * 16 + l15) * 128 + kk + quad * 8);
#pragma unroll
    for (int ni = 0; ni < 4; ni++)
      bF[ni] = *(const bf16x8*)(Ks + (ni * 16 + l15) * 128 + kk + quad * 8);
#pragma unroll
    for (int mi = 0; mi < 4; mi++)
#pragma unroll
      for (int ni = 0; ni < 4; ni++)
        acc[mi][ni] = mfma16(aF[mi], bF[ni], acc[mi][ni]);
    __syncthreads();
  }

  // combine wave partials into attnF (fp32, padded stride 66)
  for (int w = 0; w < 4; w++) {
    if (wave == w) {
#pragma unroll
      for (int mi = 0; mi < 4; mi++)
#pragma unroll
        for (int ni = 0; ni < 4; ni++)
#pragma unroll
          for (int r = 0; r < 4; r++) {
            int row = mi * 16 + quad * 4 + r, col = ni * 16 + l15;
            if (w == 0) attnF[row * 66 + col] = acc[mi][ni][r];
            else attnF[row * 66 + col] += acc[mi][ni][r];
          }
    }
    __syncthreads();
  }

  // softmax over d (cols), one lane per row, scale = 1/8
  if (wave == 0) {
    int row = lane;
    float m = -1e30f;
    for (int j = 0; j < 64; j++) m = fmaxf(m, attnF[row * 66 + j] * 0.125f);
    float s = 0.f;
    for (int j = 0; j < 64; j++) {
      float e = __expf(attnF[row * 66 + j] * 0.125f - m);
      attnF[row * 66 + j] = e;
      s += e;
    }
    float inv = 1.f / s;
    for (int j = 0; j < 64; j++) attnB[row * 64 + j] = f2bf(attnF[row * 66 + j] * inv);
  }
  __syncthreads();

  // ---- phase B: outT[n][c] = sum_d vT[n][d] * attn[c][d]; wave w owns 64-n band
  for (int n0 = 0; n0 < NN; n0 += 256) {
#pragma unroll
    for (int t = 0; t < 8; t++) {
      int q = t * 256 + tid;
      async16(vp + (size_t)(n0 + (q >> 3)) * CC + (q & 7) * 8, (char*)vTs + q * 16);
    }
    __syncthreads();
    floatx4 oacc[4][4];
#pragma unroll
    for (int i = 0; i < 4; i++)
#pragma unroll
      for (int j = 0; j < 4; j++) oacc[i][j] = (floatx4){0.f, 0.f, 0.f, 0.f};
    int nb = wave * 64;
#pragma unroll
    for (int kk = 0; kk < 64; kk += 32) {
      bf16x8 aF[4], bF[4];
#pragma unroll
      for (int mi = 0; mi < 4; mi++)
        aF[mi] = *(const bf16x8*)(vTs + (nb + mi * 16 + l15) * 64 + kk + quad * 8);
#pragma unroll
      for (int ni = 0; ni < 4; ni++)
        bF[ni] = *(const bf16x8*)(attnB + (ni * 16 + l15) * 64 + kk + quad * 8);
#pragma unroll
      for (int mi = 0; mi < 4; mi++)
#pragma unroll
        for (int ni = 0; ni < 4; ni++)
          oacc[mi][ni] = mfma16(aF[mi], bF[ni], oacc[mi][ni]);
    }
#pragma unroll
    for (int mi = 0; mi < 4; mi++)
#pragma unroll
      for (int ni = 0; ni < 4; ni++)
#pragma unroll
        for (int r = 0; r < 4; r++) {
          int n = n0 + nb + mi * 16 + quad * 4 + r;
          op[(size_t)n * CC + ni * 16 + l15] = f2bf(oacc[mi][ni][r]);
        }
    __syncthreads();
  }
}

// ---------------------------------------------------------------- launch
extern "C" void kernel_launch(void* const* d_in, const int* in_sizes, int n_in,
                              void* d_out, int out_size, void* d_ws, size_t ws_size,
                              hipStream_t stream) {
  const float* x = (const float*)d_in[0];
  const float* gn_scale = (const float*)d_in[1];
  const float* gn_bias = (const float*)d_in[2];
  const float* qkv_w = (const float*)d_in[3];
  const float* qkv_b = (const float*)d_in[4];
  const float* proj_w = (const float*)d_in[5];
  const float* proj_b = (const float*)d_in[6];
  float* out = (float*)d_out;
  char* ws = (char*)d_ws;

  // workspace layout (total ~130.04 MiB)
  unsigned short* qkbuf = (unsigned short*)(ws);                    // 64 MiB (B,1024,N)
  unsigned short* vTbuf = (unsigned short*)(ws + 67108864);         // 32 MiB (B,N,C)
  unsigned short* hT    = (unsigned short*)(ws + 100663296);        // 32 MiB (B,N,C); reused as outT
  unsigned short* wqkv  = (unsigned short*)(ws + 134217728);        // 1.5 MiB
  unsigned short* wproj = (unsigned short*)(ws + 135790592);        // 0.5 MiB
  float* cA = (float*)(ws + 136314880);                             // 16 KiB
  float* cB = (float*)(ws + 136331264);                             // 16 KiB

  cvt_bf16<<<dim3(3072), 256, 0, stream>>>(qkv_w, wqkv, 1536 * 512);
  cvt_bf16<<<dim3(1024), 256, 0, stream>>>(proj_w, wproj, 512 * 512);
  gn_stats<<<dim3(256), 256, 0, stream>>>(x, gn_scale, gn_bias, cA, cB);
  gn_transpose<<<dim3(64, 8, 8), 256, 0, stream>>>(x, cA, cB, hT);
  gemm_bt<0><<<dim3(32, 12, 8), 256, 0, stream>>>(wqkv, hT, qkv_b, nullptr,
                                                  qkbuf, vTbuf, nullptr, 1536, 512);
  attention_k<<<dim3(64), 256, 0, stream>>>(qkbuf, vTbuf, hT /*outT*/);
  gemm_bt<1><<<dim3(32, 4, 8), 256, 0, stream>>>(wproj, hT, proj_b, x,
                                                 nullptr, nullptr, out, 512, 512);
}

// Round 2
// 337.782 us; speedup vs baseline: 1.1026x; 1.1026x over previous
//
#include <hip/hip_runtime.h>
#include <cstdint>
#include <cstddef>

// Problem constants
#define BB 8
#define CC 512
#define NN 4096   // H*W
// heads = 8, dh = 64, groups = 32, group size = 16 channels

typedef __bf16 bf16x8 __attribute__((ext_vector_type(8)));
typedef float floatx4 __attribute__((ext_vector_type(4)));

__device__ __forceinline__ unsigned short f2bf(float f) {
  unsigned int u = __builtin_bit_cast(unsigned int, f);
  u += 0x7FFFu + ((u >> 16) & 1u);   // round-to-nearest-even
  return (unsigned short)(u >> 16);
}

__device__ __forceinline__ void async16(const void* g, void* l) {
  __builtin_amdgcn_global_load_lds(
      (const __attribute__((address_space(1))) unsigned int*)g,
      (__attribute__((address_space(3))) unsigned int*)l, 16, 0, 0);
}

__device__ __forceinline__ floatx4 mfma16(bf16x8 a, bf16x8 b, floatx4 c) {
  return __builtin_amdgcn_mfma_f32_16x16x32_bf16(a, b, c, 0, 0, 0);
}

// ---------------------------------------------------------------- cvt f32->bf16
__global__ void cvt_bf16(const float* __restrict__ src, unsigned short* __restrict__ dst, int n) {
  int i = blockIdx.x * 256 + threadIdx.x;
  if (i < n) dst[i] = f2bf(src[i]);
}

// ---------------------------------------------------------------- GN stats
__global__ __launch_bounds__(256) void gn_stats(
    const float* __restrict__ x, const float* __restrict__ scale,
    const float* __restrict__ bias, float* __restrict__ cA, float* __restrict__ cB) {
  int b = blockIdx.x >> 5, g = blockIdx.x & 31;
  const float4* p = (const float4*)(x + (size_t)(b * CC + g * 16) * NN);
  float s = 0.f, sq = 0.f;
  for (int i = threadIdx.x; i < 16384; i += 256) {
    float4 v = p[i];
    s += (v.x + v.y) + (v.z + v.w);
    sq += (v.x * v.x + v.y * v.y) + (v.z * v.z + v.w * v.w);
  }
#pragma unroll
  for (int off = 32; off > 0; off >>= 1) {
    s += __shfl_down(s, off);
    sq += __shfl_down(sq, off);
  }
  __shared__ float rs[4], rq[4], mv[2];
  int wave = threadIdx.x >> 6, lane = threadIdx.x & 63;
  if (lane == 0) { rs[wave] = s; rq[wave] = sq; }
  __syncthreads();
  if (threadIdx.x == 0) {
    float tS = (rs[0] + rs[1]) + (rs[2] + rs[3]);
    float tQ = (rq[0] + rq[1]) + (rq[2] + rq[3]);
    float mean = tS * (1.f / 65536.f);
    float var = tQ * (1.f / 65536.f) - mean * mean;
    mv[0] = mean;
    mv[1] = rsqrtf(var + 1e-5f);
  }
  __syncthreads();
  if (threadIdx.x < 16) {
    int c = g * 16 + threadIdx.x;
    float a = mv[1] * scale[c];
    cA[b * CC + c] = a;
    cB[b * CC + c] = bias[c] - mv[0] * a;
  }
}

// ---------------------------------------------------------------- normalize + transpose
// x (B,C,N) f32  ->  hT (B,N,C) bf16,  h = x*a[c]+b[c]
__global__ __launch_bounds__(256) void gn_transpose(
    const float* __restrict__ x, const float* __restrict__ cA,
    const float* __restrict__ cB, unsigned short* __restrict__ hT) {
  int n0 = blockIdx.x * 64, c0 = blockIdx.y * 64, b = blockIdx.z;
  __shared__ float tile[64][65];
  const float* xb = x + (size_t)(b * CC + c0) * NN + n0;
  int r = threadIdx.x >> 2, j0 = threadIdx.x & 3;
#pragma unroll
  for (int j = j0; j < 16; j += 4) {
    float4 v = *(const float4*)(xb + (size_t)r * NN + j * 4);
    tile[r][j * 4 + 0] = v.x; tile[r][j * 4 + 1] = v.y;
    tile[r][j * 4 + 2] = v.z; tile[r][j * 4 + 3] = v.w;
  }
  __syncthreads();
  int nn = threadIdx.x >> 2, cs = (threadIdx.x & 3) * 16;
  const float* a = cA + b * CC + c0 + cs;
  const float* bb = cB + b * CC + c0 + cs;
  alignas(16) unsigned short outv[16];
#pragma unroll
  for (int i = 0; i < 16; i++)
    outv[i] = f2bf(tile[cs + i][nn] * a[i] + bb[i]);
  unsigned short* dst = hT + ((size_t)b * NN + n0 + nn) * CC + c0 + cs;
  *(uint4*)dst = *(const uint4*)outv;
  *(uint4*)(dst + 8) = *(const uint4*)(outv + 8);
}

// ---------------------------------------------------------------- GEMM  D = A * BT^T
// LDS layout: row-major [128][64] bf16, but the 16B chunk index within each
// row is XOR-swizzled by (row & 7) -> quad's 16 lanes spread over all 8
// bank-groups (2-way aliasing = free) instead of 16-way conflicts.
template <int MODE>
__global__ __launch_bounds__(256) void gemm_bt(
    const unsigned short* __restrict__ A, const unsigned short* __restrict__ BT,
    const float* __restrict__ bias, const float* __restrict__ resid,
    unsigned short* __restrict__ out_qk, unsigned short* __restrict__ out_vT,
    float* __restrict__ out_f32, int M, int K) {
  __shared__ unsigned short As[128 * 64];
  __shared__ unsigned short Bs[128 * 64];
  const int b = blockIdx.z;
  const int n0 = blockIdx.x * 128;
  const int m0 = blockIdx.y * 128;
  const unsigned short* Bb = BT + (size_t)b * NN * CC;
  const int tid = threadIdx.x;
  const int lane = tid & 63, wave = tid >> 6;
  const int wr = wave >> 1, wc = wave & 1;
  const int l15 = lane & 15, quad = lane >> 4;

  floatx4 acc[4][4];
#pragma unroll
  for (int i = 0; i < 4; i++)
#pragma unroll
    for (int j = 0; j < 4; j++) acc[i][j] = (floatx4){0.f, 0.f, 0.f, 0.f};

  for (int k0 = 0; k0 < K; k0 += 64) {
#pragma unroll
    for (int t = 0; t < 4; t++) {
      int q = t * 256 + tid;
      int row = q >> 3, kc = q & 7;
      int cg = kc ^ (row & 7);   // global chunk stored at LDS chunk kc
      async16(A + (size_t)(m0 + row) * K + k0 + cg * 8, (char*)As + q * 16);
      async16(Bb + (size_t)(n0 + row) * K + k0 + cg * 8, (char*)Bs + q * 16);
    }
    __syncthreads();
#pragma unroll
    for (int kk = 0; kk < 64; kk += 32) {
      bf16x8 aF[4], bF[4];
      int g = (kk >> 3) + quad;
#pragma unroll
      for (int mi = 0; mi < 4; mi++) {
        int r = wr * 64 + mi * 16 + l15;
        aF[mi] = *(const bf16x8*)(As + r * 64 + ((g ^ (r & 7)) << 3));
      }
#pragma unroll
      for (int ni = 0; ni < 4; ni++) {
        int r = wc * 64 + ni * 16 + l15;
        bF[ni] = *(const bf16x8*)(Bs + r * 64 + ((g ^ (r & 7)) << 3));
      }
#pragma unroll
      for (int mi = 0; mi < 4; mi++)
#pragma unroll
        for (int ni = 0; ni < 4; ni++)
          acc[mi][ni] = mfma16(aF[mi], bF[ni], acc[mi][ni]);
    }
    __syncthreads();
  }

  // epilogue: C/D layout col = lane&15, row = quad*4 + r  [m89-verified]
#pragma unroll
  for (int mi = 0; mi < 4; mi++) {
    int o0 = m0 + wr * 64 + mi * 16 + quad * 4;
#pragma unroll
    for (int ni = 0; ni < 4; ni++) {
      int ncol = n0 + wc * 64 + ni * 16 + l15;
      if (MODE == 0) {
        if (m0 < 1024) {
#pragma unroll
          for (int r = 0; r < 4; r++)
            out_qk[((size_t)b * 1024 + o0 + r) * NN + ncol] =
                f2bf(acc[mi][ni][r] + bias[o0 + r]);
        } else {
          alignas(8) unsigned short pk[4];
#pragma unroll
          for (int r = 0; r < 4; r++) pk[r] = f2bf(acc[mi][ni][r] + bias[o0 + r]);
          *(uint2*)(out_vT + ((size_t)b * NN + ncol) * CC + (o0 - 1024)) = *(const uint2*)pk;
        }
      } else {
#pragma unroll
        for (int r = 0; r < 4; r++) {
          size_t idx = ((size_t)b * CC + o0 + r) * NN + ncol;
          out_f32[idx] = acc[mi][ni][r] + bias[o0 + r] + resid[idx];
        }
      }
    }
  }
}

// ---------------------------------------------------------------- attention per (b,h)
// 512 threads (8 waves). qk: (B,1024,N) bf16 (q rows 0..511, k rows 512..1023)
// vT: (B,N,C) bf16; outT: (B,N,C) bf16.
// All LDS tiles use the same XOR-chunk swizzle as gemm_bt.
__global__ __launch_bounds__(512) void attention_k(
    const unsigned short* __restrict__ qk, const unsigned short* __restrict__ vT,
    unsigned short* __restrict__ outT) {
  int bh = blockIdx.x;
  int b = bh >> 3, h = bh & 7;
  const unsigned short* qp = qk + ((size_t)b * 1024 + h * 64) * NN;
  const unsigned short* kp = qp + (size_t)512 * NN;
  const unsigned short* vp = vT + (size_t)b * NN * CC + h * 64;
  unsigned short* op = outT + (size_t)b * NN * CC + h * 64;

  __shared__ char smem[73728];
  unsigned short* Qs = (unsigned short*)smem;              // [64][256] phase A
  unsigned short* Ks = (unsigned short*)(smem + 32768);    // [64][256] phase A
  float* attnF = (float*)smem;                             // [64][67]  (overlays Qs)
  unsigned short* vTs = (unsigned short*)smem;             // [512][64] phase B (overlays all staging)
  unsigned short* attnB = (unsigned short*)(smem + 65536); // [64][64] bf16, swizzled

  int tid = threadIdx.x, lane = tid & 63, wave = tid >> 6;
  int l15 = lane & 15, quad = lane >> 4;

  // ---- phase A: attn partials; wave w covers the 32-wide band w of each 256-chunk
  floatx4 acc[4][4];
#pragma unroll
  for (int i = 0; i < 4; i++)
#pragma unroll
    for (int j = 0; j < 4; j++) acc[i][j] = (floatx4){0.f, 0.f, 0.f, 0.f};

  for (int n0 = 0; n0 < NN; n0 += 256) {
#pragma unroll
    for (int t = 0; t < 4; t++) {
      int q = t * 512 + tid;
      int row = q >> 5, c = q & 31;
      int cg = c ^ (row & 7);
      async16(qp + (size_t)row * NN + n0 + cg * 8, (char*)Qs + q * 16);
      async16(kp + (size_t)row * NN + n0 + cg * 8, (char*)Ks + q * 16);
    }
    __syncthreads();
    int g = wave * 4 + quad;   // global 16B-chunk index within the 256-wide tile
    bf16x8 aF[4], bF[4];
#pragma unroll
    for (int mi = 0; mi < 4; mi++) {
      int r = mi * 16 + l15;
      aF[mi] = *(const bf16x8*)(Qs + r * 256 + ((g ^ (r & 7)) << 3));
    }
#pragma unroll
    for (int ni = 0; ni < 4; ni++) {
      int r = ni * 16 + l15;
      bF[ni] = *(const bf16x8*)(Ks + r * 256 + ((g ^ (r & 7)) << 3));
    }
#pragma unroll
    for (int mi = 0; mi < 4; mi++)
#pragma unroll
      for (int ni = 0; ni < 4; ni++)
        acc[mi][ni] = mfma16(aF[mi], bF[ni], acc[mi][ni]);
    __syncthreads();
  }

  // combine 8 wave partials into attnF (fp32, stride 67)
  for (int w = 0; w < 8; w++) {
    if (wave == w) {
#pragma unroll
      for (int mi = 0; mi < 4; mi++)
#pragma unroll
        for (int ni = 0; ni < 4; ni++)
#pragma unroll
          for (int r = 0; r < 4; r++) {
            int row = mi * 16 + quad * 4 + r, col = ni * 16 + l15;
            if (w == 0) attnF[row * 67 + col] = acc[mi][ni][r];
            else attnF[row * 67 + col] += acc[mi][ni][r];
          }
    }
    __syncthreads();
  }

  // softmax over d (cols), one lane per row, scale = 1/8; write swizzled bf16
  if (wave == 0) {
    int row = lane;
    float m = -1e30f;
    for (int j = 0; j < 64; j++) m = fmaxf(m, attnF[row * 67 + j] * 0.125f);
    float s = 0.f;
    for (int j = 0; j < 64; j++) {
      float e = __expf(attnF[row * 67 + j] * 0.125f - m);
      attnF[row * 67 + j] = e;
      s += e;
    }
    float inv = 1.f / s;
    for (int j = 0; j < 64; j++) {
      int sw = (((j >> 3) ^ (row & 7)) << 3) + (j & 7);
      attnB[row * 64 + sw] = f2bf(attnF[row * 67 + j] * inv);
    }
  }
  __syncthreads();

  // ---- phase B: outT[n][c] = sum_d vT[n][d] * attn[c][d]; wave w owns 64-row n band
  for (int n0 = 0; n0 < NN; n0 += 512) {
#pragma unroll
    for (int t = 0; t < 8; t++) {
      int q = t * 512 + tid;
      int row = q >> 3, c = q & 7;
      int cg = c ^ (row & 7);
      async16(vp + (size_t)(n0 + row) * CC + cg * 8, (char*)vTs + q * 16);
    }
    __syncthreads();
    floatx4 oacc[4][4];
#pragma unroll
    for (int i = 0; i < 4; i++)
#pragma unroll
      for (int j = 0; j < 4; j++) oacc[i][j] = (floatx4){0.f, 0.f, 0.f, 0.f};
    int nb = wave * 64;
#pragma unroll
    for (int kk = 0; kk < 64; kk += 32) {
      bf16x8 aF[4], bF[4];
      int g = (kk >> 3) + quad;
#pragma unroll
      for (int mi = 0; mi < 4; mi++) {
        int r = nb + mi * 16 + l15;
        aF[mi] = *(const bf16x8*)(vTs + r * 64 + ((g ^ (r & 7)) << 3));
      }
#pragma unroll
      for (int ni = 0; ni < 4; ni++) {
        int r = ni * 16 + l15;
        bF[ni] = *(const bf16x8*)(attnB + r * 64 + ((g ^ (r & 7)) << 3));
      }
#pragma unroll
      for (int mi = 0; mi < 4; mi++)
#pragma unroll
        for (int ni = 0; ni < 4; ni++)
          oacc[mi][ni] = mfma16(aF[mi], bF[ni], oacc[mi][ni]);
    }
#pragma unroll
    for (int mi = 0; mi < 4; mi++)
#pragma unroll
      for (int ni = 0; ni < 4; ni++)
#pragma unroll
        for (int r = 0; r < 4; r++) {
          int n = n0 + nb + mi * 16 + quad * 4 + r;
          op[(size_t)n * CC + ni * 16 + l15] = f2bf(oacc[mi][ni][r]);
        }
    __syncthreads();
  }
}

// ---------------------------------------------------------------- launch
extern "C" void kernel_launch(void* const* d_in, const int* in_sizes, int n_in,
                              void* d_out, int out_size, void* d_ws, size_t ws_size,
                              hipStream_t stream) {
  const float* x = (const float*)d_in[0];
  const float* gn_scale = (const float*)d_in[1];
  const float* gn_bias = (const float*)d_in[2];
  const float* qkv_w = (const float*)d_in[3];
  const float* qkv_b = (const float*)d_in[4];
  const float* proj_w = (const float*)d_in[5];
  const float* proj_b = (const float*)d_in[6];
  float* out = (float*)d_out;
  char* ws = (char*)d_ws;

  // workspace layout (total ~130.04 MiB)
  unsigned short* qkbuf = (unsigned short*)(ws);                    // 64 MiB (B,1024,N)
  unsigned short* vTbuf = (unsigned short*)(ws + 67108864);         // 32 MiB (B,N,C)
  unsigned short* hT    = (unsigned short*)(ws + 100663296);        // 32 MiB (B,N,C); reused as outT
  unsigned short* wqkv  = (unsigned short*)(ws + 134217728);        // 1.5 MiB
  unsigned short* wproj = (unsigned short*)(ws + 135790592);        // 0.5 MiB
  float* cA = (float*)(ws + 136314880);                             // 16 KiB
  float* cB = (float*)(ws + 136331264);                             // 16 KiB

  cvt_bf16<<<dim3(3072), 256, 0, stream>>>(qkv_w, wqkv, 1536 * 512);
  cvt_bf16<<<dim3(1024), 256, 0, stream>>>(proj_w, wproj, 512 * 512);
  gn_stats<<<dim3(256), 256, 0, stream>>>(x, gn_scale, gn_bias, cA, cB);
  gn_transpose<<<dim3(64, 8, 8), 256, 0, stream>>>(x, cA, cB, hT);
  gemm_bt<0><<<dim3(32, 12, 8), 256, 0, stream>>>(wqkv, hT, qkv_b, nullptr,
                                                  qkbuf, vTbuf, nullptr, 1536, 512);
  attention_k<<<dim3(64), 512, 0, stream>>>(qkbuf, vTbuf, hT /*outT*/);
  gemm_bt<1><<<dim3(32, 4, 8), 256, 0, stream>>>(wproj, hT, proj_b, x,
                                                 nullptr, nullptr, out, 512, 512);
}